// Round 12
// baseline (34515.259 us; speedup 1.0000x reference)
//
#include <hip/hip_runtime.h>
#include <stdint.h>

#define NTHR 256
#define NBLKS 512

namespace cfg {
// float offsets in ws (total 35.26 MB <= proven 36.2 MB budget)
constexpr size_t F_H0    = 524288;   // [2][32][512] parity (enc fw / dec l0)
constexpr size_t F_C0    = 557056;   // [32][512]
constexpr size_t F_H1    = 573440;   // [2][32][512] parity (enc bw / dec l1)
constexpr size_t F_C1    = 606208;   // [32][512]
constexpr size_t F_ATTNS = 622592;   // [2][32][512] attn vector (parity dbuf)
constexpr size_t F_VN    = 655360;   // [512]
constexpr size_t F_CTX   = 655872;   // [32][1024]
constexpr size_t F_P0    = 688640;   // [12][32][2048] dec gates0 partials (12*65536)
constexpr size_t F_P1    = 1475072;  // [16][32][2048] dec gates1 partials
constexpr size_t F_EOUT  = 2523648;  // [32][128][1024] (write-once)
constexpr size_t F_KEYS  = 6717952;  // [32][128][512]  (write-once)
constexpr size_t F_TOTAL = 8815104;  // floats
constexpr size_t MEMSET_BYTES = F_VN * 4;  // cells + h-parity + c + attn_s
}

__device__ __forceinline__ float sigm(float x)   { return 1.0f / (1.0f + __expf(-x)); }
__device__ __forceinline__ float tanhft(float x) { return 1.0f - 2.0f / (1.0f + __expf(2.0f * x)); }

// 32-bit agent-scope access — the ONLY uncached primitive (proven)
__device__ __forceinline__ float cload(const float* p) {
  return __hip_atomic_load(p, __ATOMIC_RELAXED, __HIP_MEMORY_SCOPE_AGENT);
}
__device__ __forceinline__ void cstore(float* p, float v) {
  __hip_atomic_store(p, v, __ATOMIC_RELAXED, __HIP_MEMORY_SCOPE_AGENT);
}

// checker/broadcast grid barrier (R4-proven) + spin backoff
__device__ __forceinline__ void gbar(unsigned ep, unsigned* arr, unsigned* rel) {
  __syncthreads();
  if (blockIdx.x == 0) {
    if (threadIdx.x == 0)
      __hip_atomic_store(arr, ep, __ATOMIC_RELAXED, __HIP_MEMORY_SCOPE_AGENT);
    int s0 = threadIdx.x, s1 = threadIdx.x + 256;
    while (__hip_atomic_load(arr + s0, __ATOMIC_RELAXED, __HIP_MEMORY_SCOPE_AGENT) < ep)
      __builtin_amdgcn_s_sleep(2);
    while (__hip_atomic_load(arr + s1, __ATOMIC_RELAXED, __HIP_MEMORY_SCOPE_AGENT) < ep)
      __builtin_amdgcn_s_sleep(2);
    __syncthreads();
    __hip_atomic_store(rel + (size_t)s0 * 32, ep, __ATOMIC_RELAXED, __HIP_MEMORY_SCOPE_AGENT);
    __hip_atomic_store(rel + (size_t)s1 * 32, ep, __ATOMIC_RELAXED, __HIP_MEMORY_SCOPE_AGENT);
    __syncthreads();
  } else {
    if (threadIdx.x == 0) {
      __hip_atomic_store(arr + blockIdx.x, ep, __ATOMIC_RELAXED, __HIP_MEMORY_SCOPE_AGENT);
      while (__hip_atomic_load(rel + (size_t)blockIdx.x * 32, __ATOMIC_RELAXED,
                               __HIP_MEMORY_SCOPE_AGENT) < ep)
        __builtin_amdgcn_s_sleep(16);
    }
    __syncthreads();
  }
}

// stage A-tile [32][KWIN] into LDS — gather into regs, then write (R9-proven)
template<int KWIN, typename F>
__device__ __forceinline__ void stage(float* at, F&& f) {
  static_assert((32 * KWIN) % NTHR == 0, "tile must tile NTHR");
  constexpr int PER = (32 * KWIN) / NTHR;
  __syncthreads();
  float v[PER];
#pragma unroll
  for (int r = 0; r < PER; r++) {
    int i = threadIdx.x + NTHR * r;
    v[r] = f(i / KWIN, i % KWIN);
  }
#pragma unroll
  for (int r = 0; r < PER; r++) at[threadIdx.x + NTHR * r] = v[r];
  __syncthreads();
}

// GEMM fragment: preload ALL KQ weight rows (one latency round), then compute (R10-proven)
template<int KWIN>
__device__ __forceinline__ void gemm_frag(const float* __restrict__ W, int ldw,
                                          int n, bool nok, int kw0,
                                          const float* at, float* acc) {
  const int wave = threadIdx.x >> 6;
  constexpr int KQ = KWIN / 4;  // 16..32
  const int klo = wave * KQ;
  const float* wp = W + (size_t)(kw0 + klo) * (size_t)ldw + n;
  float w[KQ];
#pragma unroll
  for (int j = 0; j < KQ; j++) w[j] = nok ? wp[(size_t)j * ldw] : 0.f;
#pragma unroll
  for (int jj = 0; jj < KQ; jj += 4) {
    const float* ap = at + klo + jj;
#pragma unroll
    for (int m = 0; m < 32; m++) {
      float4 a = *(const float4*)(ap + m * KWIN);
      acc[m] = fmaf(a.x, w[jj + 0], acc[m]);
      acc[m] = fmaf(a.y, w[jj + 1], acc[m]);
      acc[m] = fmaf(a.z, w[jj + 2], acc[m]);
      acc[m] = fmaf(a.w, w[jj + 3], acc[m]);
    }
  }
}

// red layout [4][32][64] = 8192 floats (proven)
__device__ __forceinline__ void red_write(float* red, const float* acc) {
  const int wave = threadIdx.x >> 6, lane = threadIdx.x & 63;
  __syncthreads();
#pragma unroll
  for (int m = 0; m < 32; m++) red[(wave * 32 + m) * 64 + lane] = acc[m];
  __syncthreads();
}
__device__ __forceinline__ float redsum(const float* red, int m, int c) {
  return red[m * 64 + c] + red[2048 + m * 64 + c] +
         red[4096 + m * 64 + c] + red[6144 + m * 64 + c];
}

__device__ __forceinline__ void epi_cstore(const float* red, float* outp, int ldo, int n0) {
  for (int i = threadIdx.x; i < 2048; i += NTHR) {
    int m = i >> 6, nn = i & 63;
    cstore(outp + (size_t)m * ldo + n0 + nn, redsum(red, m, nn));
  }
}

// ALL 4 gates x NKB partial loads issued back-to-back, then sum (R10-proven)
template<int NKB>
__device__ __forceinline__ void gate_sum4(const float* base, float g4[4]) {
  float v[4][NKB];
#pragma unroll
  for (int g = 0; g < 4; g++) {
    const float* p = base + g * 512;
#pragma unroll
    for (int j = 0; j < NKB; j++) v[g][j] = cload(p + (size_t)j * 65536);
  }
#pragma unroll
  for (int g = 0; g < 4; g++) {
    float s = 0.f;
#pragma unroll
    for (int j = 0; j < NKB; j++) s += v[g][j];
    g4[g] = s;
  }
}

__global__ __launch_bounds__(NTHR, 2) void seq2seq_kernel(
    const float* __restrict__ embed_in, const float* __restrict__ dec_embed,
    const int* __restrict__ lens,
    const float* __restrict__ Wfw, const float* __restrict__ bfw,
    const float* __restrict__ Wbw, const float* __restrict__ bbw,
    const float* __restrict__ Wd0, const float* __restrict__ bd0,
    const float* __restrict__ Wd1, const float* __restrict__ bd1,
    const float* __restrict__ Wmem, const float* __restrict__ Wq,
    const float* __restrict__ battn, const float* __restrict__ vattn,
    const float* __restrict__ gattn, const float* __restrict__ Wal,
    const float* __restrict__ Wproj, const float* __restrict__ bproj,
    float* __restrict__ out, float* ws) {
  __shared__ float smem[16384];  // 64 KiB: at=[0,4096) at2=[4096,8192) red=[8192,16384)
  float* at  = smem;
  float* at2 = smem + 4096;
  float* red = smem + 8192;

  unsigned* arr = (unsigned*)ws;        // [512]
  unsigned* rel = (unsigned*)ws + 512;  // [512*32]
  float* h0p    = ws + cfg::F_H0;       // [2][32][512] parity
  float* c0     = ws + cfg::F_C0;       // plain, block-private per epoch
  float* h1p    = ws + cfg::F_H1;
  float* c1     = ws + cfg::F_C1;
  float* attn_s = ws + cfg::F_ATTNS;    // parity stride 16384
  float* vn     = ws + cfg::F_VN;
  float* ctx    = ws + cfg::F_CTX;
  float* p0     = ws + cfg::F_P0;
  float* p1     = ws + cfg::F_P1;
  float* eout   = ws + cfg::F_EOUT;
  float* keysp  = ws + cfg::F_KEYS;
  float* h0 = h0p;  // decoder single-buffer views (slot 0)
  float* h1 = h1p;

  const int bid = blockIdx.x, tid = threadIdx.x;
  const int wave = tid >> 6, lane = tid & 63;
  unsigned ep = 1;
#define BAR()  do { gbar(ep, arr, rel); ep++; } while (0)
#define BARSEAL() do { __threadfence(); gbar(ep, arr, rel); ep++; __threadfence(); } while (0)

  // ---------------- setup: normalized attention vector ----------------
  if (bid == 0) {
    float s = 0.f;
    for (int u = tid; u < 512; u += NTHR) { float x = vattn[u]; s = fmaf(x, x, s); }
#pragma unroll
    for (int off = 32; off > 0; off >>= 1) s += __shfl_xor(s, off, 64);
    if (lane == 0) at[64 + wave] = s;
    __syncthreads();
    float S = at[64] + at[65] + at[66] + at[67];
    float scale = gattn[0] / sqrtf(S);
    for (int u = tid; u < 512; u += NTHR) vn[u] = vattn[u] * scale;  // plain; sealed below
  }
  BAR();

  // ---------------- encoder: ONE fused phase/step (64 blocks) ----------------
  for (int t = 0; t < 128; t++) {
    if (bid < 64) {
      const int dir = bid >> 5, U0 = (bid & 31) * 16;
      const float* W = dir ? Wbw : Wfw;
      const float* bias = dir ? bbw : bfw;
      float* Hp = dir ? h1p : h0p;
      float* Cp = dir ? c1 : c0;
      const float* hprev = Hp + (size_t)((t + 1) & 1) * 16384;
      float* hnew = Hp + (size_t)(t & 1) * 16384;
      const int col = (lane >> 4) * 512 + U0 + (lane & 15);  // gate*512 + unit
      float acc[32];
#pragma unroll
      for (int m = 0; m < 32; m++) acc[m] = 0.f;
      float v[16];
      auto ldchunk = [&](int ch) {
#pragma unroll
        for (int r = 0; r < 16; r++) {
          int i = tid + 256 * r;
          int m = i >> 7, kl = i & 127;
          if (ch < 4) {
            int tt = t;
            if (dir) { int len = lens[m]; tt = (t < len) ? (len - 1 - t) : t; }
            v[r] = embed_in[((size_t)m * 128 + tt) * 512 + ch * 128 + kl];
          } else {
            v[r] = cload(hprev + (size_t)m * 512 + (ch - 4) * 128 + kl);
          }
        }
      };
      ldchunk(0);
#pragma unroll 1
      for (int ch = 0; ch < 8; ch++) {
        float* buf = (ch & 1) ? at2 : at;
#pragma unroll
        for (int r = 0; r < 16; r++) buf[tid + 256 * r] = v[r];
        __syncthreads();
        if (ch < 7) ldchunk(ch + 1);  // loads fly during compute below
        gemm_frag<128>(W, 2048, col, true, ch * 128, buf, acc);
        __syncthreads();
      }
      red_write(red, acc);
#pragma unroll
      for (int r = 0; r < 2; r++) {
        int idx = tid + r * 256;  // 512 outputs: (m, ul)
        int m = idx >> 4, ul = idx & 15, u = U0 + ul;
        float g4[4];
#pragma unroll
        for (int g = 0; g < 4; g++) g4[g] = redsum(red, m, g * 16 + ul) + bias[g * 512 + u];
        int len = lens[m];
        bool valid = t < len;
        float co = Cp[(size_t)m * 512 + u];   // plain (block-private)
        float cn = sigm(g4[2] + 1.f) * co + sigm(g4[0]) * tanhft(g4[1]);
        float hn = sigm(g4[3]) * tanhft(cn);
        if (valid) Cp[(size_t)m * 512 + u] = cn;
        float hp = cload(hprev + (size_t)m * 512 + u);
        float hv = valid ? hn : hp;
        cstore(hnew + (size_t)m * 512 + u, hv);
        int tpos = (dir && valid) ? (len - 1 - t) : t;
        eout[((size_t)m * 128 + tpos) * 1024 + dir * 512 + u] = valid ? hn : 0.f;  // sealed
        if (t == 127) cstore(Hp + (size_t)m * 512 + u, hv);  // final h -> slot 0 for decoder
      }
    }
    BAR();
  }
  BARSEAL();  // seal eout, vn, c0/c1 (plain) for cross-block readers

  // ---------------- keys = enc_out @ w_mem (1024 tasks) ----------------
  {
#pragma unroll 1
    for (int task = bid; task < 1024; task += NBLKS) {
      int mt = task >> 3, nb = task & 7;
      int n0 = nb * 64;
      const float* arow = eout + (size_t)mt * 32 * 1024;
      float acc[32];
#pragma unroll
      for (int m = 0; m < 32; m++) acc[m] = 0.f;
      const int n = n0 + lane;
#pragma unroll 1
      for (int c = 0; c < 8; c++) {
        stage<128>(at, [&](int m, int kl) -> float {
          return arow[(size_t)m * 1024 + c * 128 + kl];
        });
        gemm_frag<128>(Wmem, 512, n, true, c * 128, at, acc);
      }
      red_write(red, acc);
      for (int i = tid; i < 2048; i += NTHR) {
        int m = i >> 6, nn = i & 63;
        keysp[(size_t)mt * 32 * 512 + (size_t)m * 512 + n0 + nn] = redsum(red, m, nn);
      }
    }
  }
  BARSEAL();  // seal keys

  // ---------------- decoder loop (t==128: trailing projection only) ----------------
  for (int t = 0; t <= 128; t++) {
    if (t < 128) {
      // phase A: gates0 GEMM, K=1536 = x(512)|attn(t-1)(512)|h0(512)
      // 384 blocks: 32nb x 12kb, KWIN=128  (matches p0[12] layout + gate_sum4<12>)
      if (bid < 384) {
        int nb = bid & 31, kb = bid >> 5;  // kb 0..11
        const float* asrc = attn_s + (size_t)((t + 1) & 1) * 16384;  // attn(t-1)
        stage<128>(at, [&](int m, int kl) -> float {
          int kk = kb * 128 + kl;
          if (kk < 512) return dec_embed[((size_t)m * 128 + t) * 512 + kk];
          if (kk < 1024) return cload(asrc + m * 512 + kk - 512);
          return cload(h0 + m * 512 + kk - 1024);
        });
        float acc[32];
#pragma unroll
        for (int m = 0; m < 32; m++) acc[m] = 0.f;
        gemm_frag<128>(Wd0, 2048, nb * 64 + lane, true, kb * 128, at, acc);
        red_write(red, acc);
        epi_cstore(red, p0 + (size_t)kb * 65536, 2048, nb * 64);
      }
      BAR();
    }

    // phase B: act0 (0..63) + zero attn_s[t&1] (64..71)  ||  proj(t-1) full-K (72..212)
    if (t < 128 && bid < 64) {
      int p = bid * NTHR + tid;
      int m = p >> 9, u = p & 511;
      float g4[4];
      gate_sum4<12>(p0 + m * 2048 + u, g4);
#pragma unroll
      for (int g = 0; g < 4; g++) g4[g] += bd0[g * 512 + u];
      float co = c0[(size_t)m * 512 + u];          // plain (block-private)
      float cn = sigm(g4[2] + 1.f) * co + sigm(g4[0]) * tanhft(g4[1]);
      float hn = sigm(g4[3]) * tanhft(cn);
      c0[(size_t)m * 512 + u] = cn;
      cstore(h0 + (size_t)m * 512 + u, hn);
    } else if (t < 128 && bid < 72) {
      float* az = attn_s + (size_t)(t & 1) * 16384 + (size_t)(bid - 64) * 2048;
      for (int i = tid; i < 2048; i += NTHR) cstore(az + i, 0.f);
    } else if (bid >= 72 && bid < 213 && t >= 1) {
      // projection of step t-1: full K=512 per block, pipelined 4-chunk staging,
      // plain stores (no atomics)
      int nb = bid - 72;
      int n0 = nb * 64;
      const float* asrc = attn_s + (size_t)((t + 1) & 1) * 16384;  // attn(t-1)
      const int col = n0 + lane;
      const bool ok = col < 9000;
      float acc[32];
#pragma unroll
      for (int m = 0; m < 32; m++) acc[m] = 0.f;
      float v[16];
      auto ldc = [&](int c) {
#pragma unroll
        for (int r = 0; r < 16; r++) {
          int i = tid + 256 * r;
          int m = i >> 7, kl = i & 127;
          v[r] = cload(asrc + (size_t)m * 512 + c * 128 + kl);
        }
      };
      ldc(0);
#pragma unroll 1
      for (int c = 0; c < 4; c++) {
        float* buf = (c & 1) ? at2 : at;
#pragma unroll
        for (int r = 0; r < 16; r++) buf[tid + 256 * r] = v[r];
        __syncthreads();
        if (c < 3) ldc(c + 1);
        gemm_frag<128>(Wproj, 9000, col, ok, c * 128, buf, acc);
        __syncthreads();
      }
      red_write(red, acc);
      for (int i = tid; i < 2048; i += NTHR) {
        int m = i >> 6, nn = i & 63;
        int nc = n0 + nn;
        if (nc < 9000)
          out[((size_t)m * 128 + (t - 1)) * 9000 + nc] = redsum(red, m, nn) + bproj[nc];
      }
    }
    BAR();

    if (t < 128) {
      // phase C: gates1 GEMM, K=1024 = h0new|h1old; 32nb x 16kb, KWIN=64
      {
        int nb = bid & 31, kb = bid >> 5;
        stage<64>(at, [&](int m, int kl) -> float {
          int kk = kb * 64 + kl;
          return (kk < 512) ? cload(h0 + m * 512 + kk) : cload(h1 + m * 512 + kk - 512);
        });
        float acc[32];
#pragma unroll
        for (int m = 0; m < 32; m++) acc[m] = 0.f;
        gemm_frag<64>(Wd1, 2048, nb * 64 + lane, true, kb * 64, at, acc);
        red_write(red, acc);
        epi_cstore(red, p1 + (size_t)kb * 65536, 2048, nb * 64);
      }
      BAR();

      // phase E: attention, one block per batch row (blocks 0..31)
      if (bid < 32) {
        int b = bid;
        int len = lens[b];
        float* sh_h1v = at;          // 512
        float* sh_qb  = at + 512;    // 512
        float* sh_vnv = at + 1024;   // 512
        float* sh_sc  = at + 1536;   // 128
        float* sh_al  = at + 1664;   // 128
        float* sh_r   = at + 1792;   // 16
        float* redq   = at + 2048;   // 2048 (ends at at[4096))
        // act1 for row b (sole writer; c1 plain block-private)
#pragma unroll 1
        for (int u = tid; u < 512; u += NTHR) {
          float g4[4];
          gate_sum4<16>(p1 + b * 2048 + u, g4);
#pragma unroll
          for (int g = 0; g < 4; g++) g4[g] += bd1[g * 512 + u];
          float co = c1[(size_t)b * 512 + u];
          float cn = sigm(g4[2] + 1.f) * co + sigm(g4[0]) * tanhft(g4[1]);
          float hn = sigm(g4[3]) * tanhft(cn);
          c1[(size_t)b * 512 + u] = cn;
          cstore(h1 + (size_t)b * 512 + u, hn);
          sh_h1v[u] = hn;
          sh_vnv[u] = vn[u];
        }
        __syncthreads();
        // q = h1n @ w_query — batched x8
        {
          float4 qa = make_float4(0.f, 0.f, 0.f, 0.f), qb4 = make_float4(0.f, 0.f, 0.f, 0.f);
          const int ua = lane * 4, ub = 256 + lane * 4;
          const float* wqp = Wq + (size_t)(wave * 128) * 512;
#pragma unroll 1
          for (int kk = 0; kk < 128; kk += 8) {
            float4 wa[8], wb[8];
#pragma unroll
            for (int j = 0; j < 8; j++) {
              wa[j] = *(const float4*)(wqp + (size_t)(kk + j) * 512 + ua);
              wb[j] = *(const float4*)(wqp + (size_t)(kk + j) * 512 + ub);
            }
#pragma unroll
            for (int j = 0; j < 8; j++) {
              float h = sh_h1v[wave * 128 + kk + j];
              qa.x = fmaf(h, wa[j].x, qa.x); qa.y = fmaf(h, wa[j].y, qa.y);
              qa.z = fmaf(h, wa[j].z, qa.z); qa.w = fmaf(h, wa[j].w, qa.w);
              qb4.x = fmaf(h, wb[j].x, qb4.x); qb4.y = fmaf(h, wb[j].y, qb4.y);
              qb4.z = fmaf(h, wb[j].z, qb4.z); qb4.w = fmaf(h, wb[j].w, qb4.w);
            }
          }
          *(float4*)(redq + wave * 512 + ua) = qa;
          *(float4*)(redq + wave * 512 + ub) = qb4;
        }
        __syncthreads();
        for (int u = tid; u < 512; u += NTHR)
          sh_qb[u] = redq[u] + redq[512 + u] + redq[1024 + u] + redq[1536 + u] + battn[u];
        __syncthreads();
        // scores — batched x4
#pragma unroll 1
        for (int tt = 0; tt < 32; tt += 4) {
          float4 kv[4][2];
#pragma unroll
          for (int j = 0; j < 4; j++) {
            const float* kp = keysp + ((size_t)b * 128 + wave * 32 + tt + j) * 512;
            kv[j][0] = *(const float4*)(kp + lane * 4);
            kv[j][1] = *(const float4*)(kp + lane * 4 + 256);
          }
#pragma unroll
          for (int j = 0; j < 4; j++) {
            int tq = wave * 32 + tt + j;
            float s = 0.f;
#pragma unroll
            for (int hh = 0; hh < 2; hh++) {
              int u = lane * 4 + hh * 256;
              float4 k4 = kv[j][hh];
              s += sh_vnv[u + 0] * tanhft(k4.x + sh_qb[u + 0]);
              s += sh_vnv[u + 1] * tanhft(k4.y + sh_qb[u + 1]);
              s += sh_vnv[u + 2] * tanhft(k4.z + sh_qb[u + 2]);
              s += sh_vnv[u + 3] * tanhft(k4.w + sh_qb[u + 3]);
            }
#pragma unroll
            for (int off = 32; off > 0; off >>= 1) s += __shfl_xor(s, off, 64);
            if (lane == 0) sh_sc[tq] = (tq < len) ? s : -1e30f;
          }
        }
        __syncthreads();
        // softmax over 128
        {
          float v = (tid < 128) ? sh_sc[tid] : -1e30f;
          float mx = v;
#pragma unroll
          for (int off = 32; off > 0; off >>= 1) mx = fmaxf(mx, __shfl_xor(mx, off, 64));
          if (lane == 0) sh_r[wave] = mx;
          __syncthreads();
          mx = fmaxf(fmaxf(sh_r[0], sh_r[1]), fmaxf(sh_r[2], sh_r[3]));
          float e = (tid < 128 && tid < len) ? __expf(v - mx) : 0.f;
          float sum = e;
#pragma unroll
          for (int off = 32; off > 0; off >>= 1) sum += __shfl_xor(sum, off, 64);
          if (lane == 0) sh_r[8 + wave] = sum;
          __syncthreads();
          float inv = 1.f / (sh_r[8] + sh_r[9] + sh_r[10] + sh_r[11]);
          if (tid < 128) sh_al[tid] = e * inv;   // 0 for masked entries
        }
        __syncthreads();
        // context = alpha @ enc_out[b] — batched x8; masked rows have alpha=0
        {
          int d = tid * 4;
          float4 acc = make_float4(0.f, 0.f, 0.f, 0.f);
          const float* ep2 = eout + (size_t)b * 128 * 1024 + d;
#pragma unroll 1
          for (int tq0 = 0; tq0 < 128; tq0 += 8) {
            float4 e4[8];
#pragma unroll
            for (int j = 0; j < 8; j++)
              e4[j] = *(const float4*)(ep2 + (size_t)(tq0 + j) * 1024);
#pragma unroll
            for (int j = 0; j < 8; j++) {
              float a = sh_al[tq0 + j];
              acc.x = fmaf(a, e4[j].x, acc.x); acc.y = fmaf(a, e4[j].y, acc.y);
              acc.z = fmaf(a, e4[j].z, acc.z); acc.w = fmaf(a, e4[j].w, acc.w);
            }
          }
          cstore(ctx + b * 1024 + d + 0, acc.x);
          cstore(ctx + b * 1024 + d + 1, acc.y);
          cstore(ctx + b * 1024 + d + 2, acc.z);
          cstore(ctx + b * 1024 + d + 3, acc.w);
        }
      }
      BAR();

      // phase F: attn(t) = (h1|ctx) @ Wal; 8nb x 16kb = 128 blocks, KWIN=96
      if (bid < 128) {
        int nb = bid & 7, kb = bid >> 3;
        stage<96>(at, [&](int m, int kl) -> float {
          int kk = kb * 96 + kl;
          return (kk < 512) ? cload(h1 + m * 512 + kk) : cload(ctx + m * 1024 + kk - 512);
        });
        float acc[32];
#pragma unroll
        for (int m = 0; m < 32; m++) acc[m] = 0.f;
        gemm_frag<96>(Wal, 512, nb * 64 + lane, true, kb * 96, at, acc);
        red_write(red, acc);
        float* adst = attn_s + (size_t)(t & 1) * 16384;
        for (int i = tid; i < 2048; i += NTHR) {
          int m = i >> 6, nn = i & 63;
          atomicAdd(adst + (size_t)m * 512 + nb * 64 + nn, redsum(red, m, nn));
        }
      }
      BAR();
    }
  }
#undef BAR
#undef BARSEAL
}

extern "C" void kernel_launch(void* const* d_in, const int* in_sizes, int n_in,
                              void* d_out, int out_size, void* d_ws, size_t ws_size,
                              hipStream_t stream) {
  (void)in_sizes; (void)n_in; (void)out_size; (void)ws_size;
  hipMemsetAsync(d_ws, 0, cfg::MEMSET_BYTES, stream);  // cells + h-parity + c + attn_s
  hipLaunchKernelGGL(seq2seq_kernel, dim3(NBLKS), dim3(NTHR), 0, stream,
                     (const float*)d_in[0],   // embed_in
                     (const float*)d_in[1],   // dec_embed
                     (const int*)d_in[2],     // in_seq_len
                     (const float*)d_in[3],   // enc_fw_kernel
                     (const float*)d_in[4],   // enc_fw_bias
                     (const float*)d_in[5],   // enc_bw_kernel
                     (const float*)d_in[6],   // enc_bw_bias
                     (const float*)d_in[7],   // dec_kernel0
                     (const float*)d_in[8],   // dec_bias0
                     (const float*)d_in[9],   // dec_kernel1
                     (const float*)d_in[10],  // dec_bias1
                     (const float*)d_in[11],  // w_mem
                     (const float*)d_in[12],  // w_query
                     (const float*)d_in[13],  // b_attn
                     (const float*)d_in[14],  // v_attn
                     (const float*)d_in[15],  // g_attn
                     (const float*)d_in[16],  // w_attn_layer
                     (const float*)d_in[17],  // w_proj
                     (const float*)d_in[18],  // b_proj
                     (float*)d_out, (float*)d_ws);
}

// Round 13
// 19018.280 us; speedup vs baseline: 1.8148x; 1.8148x over previous
//
#include <hip/hip_runtime.h>
#include <stdint.h>

#define NTHR 256
#define NBLKS 512

namespace cfg {
// ws layout in FLOAT units (R10 layout; p0/p1 region repurposed as aall)
constexpr size_t F_CELLS = 0;                     // arr[512] u32 + rel[512*32] u32
constexpr size_t F_H0    = 524288;                // [32][512]
constexpr size_t F_C0    = F_H0 + 16384;
constexpr size_t F_H1    = F_C0 + 16384;
constexpr size_t F_C1    = F_H1 + 16384;
constexpr size_t F_ATTNS = F_C1 + 16384;          // [2][32][512] attn vector (parity dbuf)
constexpr size_t F_VN    = F_ATTNS + 32768;       // [512]
constexpr size_t F_CTX   = F_VN + 512;            // [32][1024]
constexpr size_t F_AALL  = F_CTX + 32768;         // [128][32][512] attn history (2097152)
constexpr size_t F_EOUT  = F_AALL + 2097152;      // [32][128][1024] (write-once)
constexpr size_t F_KEYS  = F_EOUT + 4194304;      // [32][128][512]  (write-once)
constexpr size_t F_TOTAL = F_KEYS + 2097152;      // ~36.2 MB (proven budget)
constexpr size_t MEMSET_BYTES = F_VN * 4;         // cells + states + attn_s
// gate-partial scratch lives in the OUT buffer (dead until final projection):
constexpr size_t O_P0 = 0;        // [12][32][2048] = 786432 floats
constexpr size_t O_P1 = 786432;   // [16][32][2048] = 1048576 floats
}

__device__ __forceinline__ float sigm(float x)   { return 1.0f / (1.0f + __expf(-x)); }
__device__ __forceinline__ float tanhft(float x) { return 1.0f - 2.0f / (1.0f + __expf(2.0f * x)); }

// 32-bit agent-scope access — the ONLY uncached primitive (proven)
__device__ __forceinline__ float cload(const float* p) {
  return __hip_atomic_load(p, __ATOMIC_RELAXED, __HIP_MEMORY_SCOPE_AGENT);
}
__device__ __forceinline__ void cstore(float* p, float v) {
  __hip_atomic_store(p, v, __ATOMIC_RELAXED, __HIP_MEMORY_SCOPE_AGENT);
}

// checker/broadcast grid barrier (R4-proven, unchanged)
__device__ __forceinline__ void gbar(unsigned ep, unsigned* arr, unsigned* rel) {
  __syncthreads();
  if (blockIdx.x == 0) {
    if (threadIdx.x == 0)
      __hip_atomic_store(arr, ep, __ATOMIC_RELAXED, __HIP_MEMORY_SCOPE_AGENT);
    int s0 = threadIdx.x, s1 = threadIdx.x + 256;
    while (__hip_atomic_load(arr + s0, __ATOMIC_RELAXED, __HIP_MEMORY_SCOPE_AGENT) < ep)
      __builtin_amdgcn_s_sleep(1);
    while (__hip_atomic_load(arr + s1, __ATOMIC_RELAXED, __HIP_MEMORY_SCOPE_AGENT) < ep)
      __builtin_amdgcn_s_sleep(1);
    __syncthreads();
    __hip_atomic_store(rel + (size_t)s0 * 32, ep, __ATOMIC_RELAXED, __HIP_MEMORY_SCOPE_AGENT);
    __hip_atomic_store(rel + (size_t)s1 * 32, ep, __ATOMIC_RELAXED, __HIP_MEMORY_SCOPE_AGENT);
    __syncthreads();
  } else {
    if (threadIdx.x == 0) {
      __hip_atomic_store(arr + blockIdx.x, ep, __ATOMIC_RELAXED, __HIP_MEMORY_SCOPE_AGENT);
      while (__hip_atomic_load(rel + (size_t)blockIdx.x * 32, __ATOMIC_RELAXED,
                               __HIP_MEMORY_SCOPE_AGENT) < ep)
        __builtin_amdgcn_s_sleep(1);
    }
    __syncthreads();
  }
}

// stage A-tile [32][KWIN] into LDS — gather into regs, then write (R9-proven)
template<int KWIN, typename F>
__device__ __forceinline__ void stage(float* at, F&& f) {
  static_assert((32 * KWIN) % NTHR == 0, "tile must tile NTHR");
  constexpr int PER = (32 * KWIN) / NTHR;
  __syncthreads();
  float v[PER];
#pragma unroll
  for (int r = 0; r < PER; r++) {
    int i = threadIdx.x + NTHR * r;
    v[r] = f(i / KWIN, i % KWIN);
  }
#pragma unroll
  for (int r = 0; r < PER; r++) at[threadIdx.x + NTHR * r] = v[r];
  __syncthreads();
}

// GEMM fragment: preload ALL KQ weight rows (one latency round), then compute (R10-proven)
template<int KWIN>
__device__ __forceinline__ void gemm_frag(const float* __restrict__ W, int ldw,
                                          int n, bool nok, int kw0,
                                          const float* at, float* acc) {
  const int wave = threadIdx.x >> 6;
  constexpr int KQ = KWIN / 4;  // 16..32
  const int klo = wave * KQ;
  const float* wp = W + (size_t)(kw0 + klo) * (size_t)ldw + n;
  float w[KQ];
#pragma unroll
  for (int j = 0; j < KQ; j++) w[j] = nok ? wp[(size_t)j * ldw] : 0.f;
#pragma unroll
  for (int jj = 0; jj < KQ; jj += 4) {
    const float* ap = at + klo + jj;
#pragma unroll
    for (int m = 0; m < 32; m++) {
      float4 a = *(const float4*)(ap + m * KWIN);
      acc[m] = fmaf(a.x, w[jj + 0], acc[m]);
      acc[m] = fmaf(a.y, w[jj + 1], acc[m]);
      acc[m] = fmaf(a.z, w[jj + 2], acc[m]);
      acc[m] = fmaf(a.w, w[jj + 3], acc[m]);
    }
  }
}

// red layout [4][32][64] = 8192 floats (proven)
__device__ __forceinline__ void red_write(float* red, const float* acc) {
  const int wave = threadIdx.x >> 6, lane = threadIdx.x & 63;
  __syncthreads();
#pragma unroll
  for (int m = 0; m < 32; m++) red[(wave * 32 + m) * 64 + lane] = acc[m];
  __syncthreads();
}
__device__ __forceinline__ float redsum(const float* red, int m, int c) {
  return red[m * 64 + c] + red[2048 + m * 64 + c] +
         red[4096 + m * 64 + c] + red[6144 + m * 64 + c];
}

__device__ __forceinline__ void epi_cstore(const float* red, float* outp, int ldo, int n0) {
  for (int i = threadIdx.x; i < 2048; i += NTHR) {
    int m = i >> 6, nn = i & 63;
    cstore(outp + (size_t)m * ldo + n0 + nn, redsum(red, m, nn));
  }
}

// ALL 4 gates x NKB partial loads issued back-to-back, then sum (R10-proven)
template<int NKB>
__device__ __forceinline__ void gate_sum4(const float* base, float g4[4]) {
  float v[4][NKB];
#pragma unroll
  for (int g = 0; g < 4; g++) {
    const float* p = base + g * 512;
#pragma unroll
    for (int j = 0; j < NKB; j++) v[g][j] = cload(p + (size_t)j * 65536);
  }
#pragma unroll
  for (int g = 0; g < 4; g++) {
    float s = 0.f;
#pragma unroll
    for (int j = 0; j < NKB; j++) s += v[g][j];
    g4[g] = s;
  }
}

__global__ __launch_bounds__(NTHR, 2) void seq2seq_kernel(
    const float* __restrict__ embed_in, const float* __restrict__ dec_embed,
    const int* __restrict__ lens,
    const float* __restrict__ Wfw, const float* __restrict__ bfw,
    const float* __restrict__ Wbw, const float* __restrict__ bbw,
    const float* __restrict__ Wd0, const float* __restrict__ bd0,
    const float* __restrict__ Wd1, const float* __restrict__ bd1,
    const float* __restrict__ Wmem, const float* __restrict__ Wq,
    const float* __restrict__ battn, const float* __restrict__ vattn,
    const float* __restrict__ gattn, const float* __restrict__ Wal,
    const float* __restrict__ Wproj, const float* __restrict__ bproj,
    float* __restrict__ out, float* ws) {
  __shared__ float smem[12288];  // 48 KiB: at=[0,4096), red=[4096,12288)
  float* at  = smem;
  float* red = smem + 4096;

  unsigned* arr = (unsigned*)ws;        // [512]
  unsigned* rel = (unsigned*)ws + 512;  // [512*32]
  float* h0     = ws + cfg::F_H0;
  float* c0     = ws + cfg::F_C0;
  float* h1     = ws + cfg::F_H1;
  float* c1     = ws + cfg::F_C1;
  float* attn_s = ws + cfg::F_ATTNS;  // parity stride 16384
  float* vn     = ws + cfg::F_VN;
  float* ctx    = ws + cfg::F_CTX;
  float* aall   = ws + cfg::F_AALL;   // [128][32][512]
  float* eout   = ws + cfg::F_EOUT;
  float* keysp  = ws + cfg::F_KEYS;
  float* p0     = out + cfg::O_P0;    // gate-partial scratch in OUT buffer
  float* p1     = out + cfg::O_P1;    // (dead by the time projection writes)

  const int bid = blockIdx.x, tid = threadIdx.x;
  const int wave = tid >> 6, lane = tid & 63;
  unsigned ep = 1;
#define BAR()  do { gbar(ep, arr, rel); ep++; } while (0)
#define BARSEAL() do { __threadfence(); gbar(ep, arr, rel); ep++; __threadfence(); } while (0)

  // ---------------- setup: normalized attention vector ----------------
  if (bid == 0) {
    float s = 0.f;
    for (int u = tid; u < 512; u += NTHR) { float x = vattn[u]; s = fmaf(x, x, s); }
#pragma unroll
    for (int off = 32; off > 0; off >>= 1) s += __shfl_xor(s, off, 64);
    if (lane == 0) at[64 + wave] = s;
    __syncthreads();
    float S = at[64] + at[65] + at[66] + at[67];
    float scale = gattn[0] / sqrtf(S);
    for (int u = tid; u < 512; u += NTHR) vn[u] = vattn[u] * scale;  // plain; sealed below
  }
  BAR();

  // ---------------- bidirectional encoder (R10 structure) ----------------
  for (int t = 0; t < 128; t++) {
    // phase A: fw+bw gate GEMMs: 2dir x 32nb x 8kb = 512 blocks, KWIN=128
    {
      int dir = bid >> 8;
      int r = bid & 255;
      int nb = r & 31, kb = r >> 5;
      const float* W = dir ? Wbw : Wfw;
      const float* hs = dir ? h1 : h0;
      stage<128>(at, [&](int m, int kl) -> float {
        int kk = kb * 128 + kl;
        if (kk < 512) {
          int tt = t;
          if (dir) { int len = lens[m]; tt = (t < len) ? (len - 1 - t) : t; }
          return embed_in[((size_t)m * 128 + tt) * 512 + kk];  // read-only cached
        }
        return cload(hs + m * 512 + kk - 512);
      });
      float acc[32];
#pragma unroll
      for (int m = 0; m < 32; m++) acc[m] = 0.f;
      gemm_frag<128>(W, 2048, nb * 64 + lane, true, kb * 128, at, acc);
      red_write(red, acc);
      epi_cstore(red, (dir ? p1 : p0) + (size_t)kb * 65536, 2048, nb * 64);
    }
    BAR();
    // phase B: activations + masked state update + enc_out write (128 blocks)
    if (bid < 128) {
      int dir = bid >> 6;
      int p = (bid & 63) * NTHR + tid;  // 0..16383
      int m = p >> 9, u = p & 511;
      const float* parts = dir ? p1 : p0;
      const float* bias  = dir ? bbw : bfw;
      float* hs = dir ? h1 : h0;
      float* cs = dir ? c1 : c0;
      float g4[4];
      gate_sum4<8>(parts + m * 2048 + u, g4);
#pragma unroll
      for (int g = 0; g < 4; g++) g4[g] += bias[g * 512 + u];
      int len = lens[m];
      bool valid = t < len;
      float co = cload(cs + m * 512 + u);
      float cn = sigm(g4[2] + 1.f) * co + sigm(g4[0]) * tanhft(g4[1]);
      float hn = sigm(g4[3]) * tanhft(cn);
      if (valid) { cstore(cs + m * 512 + u, cn); cstore(hs + m * 512 + u, hn); }
      int tpos = dir ? (valid ? (len - 1 - t) : t) : t;
      eout[((size_t)m * 128 + tpos) * 1024 + dir * 512 + u] = valid ? hn : 0.f;  // sealed
    }
    BAR();
  }

  BARSEAL();  // seal eout + vn

  // ---------------- keys = enc_out @ w_mem (M=4096, N=512, K=1024) ----------------
  {
#pragma unroll 1
    for (int task = bid; task < 1024; task += NBLKS) {
      int mt = task >> 3, nb = task & 7;
      int n0 = nb * 64;
      const float* arow = eout + (size_t)mt * 32 * 1024;
      float acc[32];
#pragma unroll
      for (int m = 0; m < 32; m++) acc[m] = 0.f;
      const int n = n0 + lane;
#pragma unroll 1
      for (int c = 0; c < 8; c++) {
        stage<128>(at, [&](int m, int kl) -> float {
          return arow[(size_t)m * 1024 + c * 128 + kl];
        });
        gemm_frag<128>(Wmem, 512, n, true, c * 128, at, acc);
      }
      red_write(red, acc);
      for (int i = tid; i < 2048; i += NTHR) {
        int m = i >> 6, nn = i & 63;
        keysp[(size_t)mt * 32 * 512 + (size_t)m * 512 + n0 + nn] = redsum(red, m, nn);
      }
    }
  }
  BARSEAL();  // seal keys

  // ---------------- decoder loop (5 phases/step; projection deferred) ----------------
  for (int t = 0; t < 128; t++) {
    // phase A: gates0 GEMM, K=1536 = x|attn(t-1)|h0; 32nb x 12kb = 384 blocks, KWIN=128
    //          || blocks 384..391: copy attn(t-1) -> aall[t-1] (plain stores; sealed later)
    if (bid < 384) {
      int nb = bid & 31, kb = bid >> 5;  // kb 0..11
      const float* asrc = attn_s + (size_t)((t + 1) & 1) * 16384;  // attn(t-1)
      stage<128>(at, [&](int m, int kl) -> float {
        int kk = kb * 128 + kl;
        if (kk < 512) return dec_embed[((size_t)m * 128 + t) * 512 + kk];
        if (kk < 1024) return cload(asrc + m * 512 + kk - 512);
        return cload(h0 + m * 512 + kk - 1024);
      });
      float acc[32];
#pragma unroll
      for (int m = 0; m < 32; m++) acc[m] = 0.f;
      gemm_frag<128>(Wd0, 2048, nb * 64 + lane, true, kb * 128, at, acc);
      red_write(red, acc);
      epi_cstore(red, p0 + (size_t)kb * 65536, 2048, nb * 64);
    } else if (bid < 392 && t >= 1) {
      const float* asrc = attn_s + (size_t)((t + 1) & 1) * 16384;  // attn(t-1)
      float v[8];
      int j8 = ((bid - 384) * 256 + tid) * 8;
#pragma unroll
      for (int k = 0; k < 8; k++) v[k] = cload(asrc + j8 + k);
#pragma unroll
      for (int k = 0; k < 8; k++) aall[(size_t)(t - 1) * 16384 + j8 + k] = v[k];
    }
    BAR();

    // phase B: act0 (blocks 0..63) + zero attn_s[t&1] (64..71) — short phase
    if (bid < 64) {
      int p = bid * NTHR + tid;
      int m = p >> 9, u = p & 511;
      float g4[4];
      gate_sum4<12>(p0 + m * 2048 + u, g4);
#pragma unroll
      for (int g = 0; g < 4; g++) g4[g] += bd0[g * 512 + u];
      float co = cload(c0 + m * 512 + u);
      float cn = sigm(g4[2] + 1.f) * co + sigm(g4[0]) * tanhft(g4[1]);
      float hn = sigm(g4[3]) * tanhft(cn);
      cstore(c0 + m * 512 + u, cn);
      cstore(h0 + m * 512 + u, hn);
    } else if (bid < 72) {
      float* az = attn_s + (size_t)(t & 1) * 16384 + (size_t)(bid - 64) * 2048;
      for (int i = tid; i < 2048; i += NTHR) cstore(az + i, 0.f);
    }
    BAR();

    // phase C: gates1 GEMM, K=1024 = h0new|h1old; 32nb x 16kb, KWIN=64
    {
      int nb = bid & 31, kb = bid >> 5;
      stage<64>(at, [&](int m, int kl) -> float {
        int kk = kb * 64 + kl;
        return (kk < 512) ? cload(h0 + m * 512 + kk) : cload(h1 + m * 512 + kk - 512);
      });
      float acc[32];
#pragma unroll
      for (int m = 0; m < 32; m++) acc[m] = 0.f;
      gemm_frag<64>(Wd1, 2048, nb * 64 + lane, true, kb * 64, at, acc);
      red_write(red, acc);
      epi_cstore(red, p1 + (size_t)kb * 65536, 2048, nb * 64);
    }
    BAR();

    // phase E: attention, one block per batch row (blocks 0..31)
    if (bid < 32) {
      int b = bid;
      int len = lens[b];
      float* sh_h1v = at;          // 512
      float* sh_qb  = at + 512;    // 512
      float* sh_vnv = at + 1024;   // 512
      float* sh_sc  = at + 1536;   // 128
      float* sh_al  = at + 1664;   // 128
      float* sh_r   = at + 1792;   // 16
      float* redq   = at + 2048;   // 2048 (ends at at[4096))
      // act1 for row b (sole writer; batched partial loads)
#pragma unroll 1
      for (int u = tid; u < 512; u += NTHR) {
        float g4[4];
        gate_sum4<16>(p1 + b * 2048 + u, g4);
#pragma unroll
        for (int g = 0; g < 4; g++) g4[g] += bd1[g * 512 + u];
        float co = cload(c1 + b * 512 + u);
        float cn = sigm(g4[2] + 1.f) * co + sigm(g4[0]) * tanhft(g4[1]);
        float hn = sigm(g4[3]) * tanhft(cn);
        cstore(c1 + b * 512 + u, cn);
        cstore(h1 + b * 512 + u, hn);
        sh_h1v[u] = hn;
        sh_vnv[u] = vn[u];
      }
      __syncthreads();
      // q = h1n @ w_query — batched x8
      {
        float4 qa = make_float4(0.f, 0.f, 0.f, 0.f), qb4 = make_float4(0.f, 0.f, 0.f, 0.f);
        const int ua = lane * 4, ub = 256 + lane * 4;
        const float* wqp = Wq + (size_t)(wave * 128) * 512;
#pragma unroll 1
        for (int kk = 0; kk < 128; kk += 8) {
          float4 wa[8], wb[8];
#pragma unroll
          for (int j = 0; j < 8; j++) {
            wa[j] = *(const float4*)(wqp + (size_t)(kk + j) * 512 + ua);
            wb[j] = *(const float4*)(wqp + (size_t)(kk + j) * 512 + ub);
          }
#pragma unroll
          for (int j = 0; j < 8; j++) {
            float h = sh_h1v[wave * 128 + kk + j];
            qa.x = fmaf(h, wa[j].x, qa.x); qa.y = fmaf(h, wa[j].y, qa.y);
            qa.z = fmaf(h, wa[j].z, qa.z); qa.w = fmaf(h, wa[j].w, qa.w);
            qb4.x = fmaf(h, wb[j].x, qb4.x); qb4.y = fmaf(h, wb[j].y, qb4.y);
            qb4.z = fmaf(h, wb[j].z, qb4.z); qb4.w = fmaf(h, wb[j].w, qb4.w);
          }
        }
        *(float4*)(redq + wave * 512 + ua) = qa;
        *(float4*)(redq + wave * 512 + ub) = qb4;
      }
      __syncthreads();
      for (int u = tid; u < 512; u += NTHR)
        sh_qb[u] = redq[u] + redq[512 + u] + redq[1024 + u] + redq[1536 + u] + battn[u];
      __syncthreads();
      // scores — batched x4
#pragma unroll 1
      for (int tt = 0; tt < 32; tt += 4) {
        float4 kv[4][2];
#pragma unroll
        for (int j = 0; j < 4; j++) {
          const float* kp = keysp + ((size_t)b * 128 + wave * 32 + tt + j) * 512;
          kv[j][0] = *(const float4*)(kp + lane * 4);
          kv[j][1] = *(const float4*)(kp + lane * 4 + 256);
        }
#pragma unroll
        for (int j = 0; j < 4; j++) {
          int tq = wave * 32 + tt + j;
          float s = 0.f;
#pragma unroll
          for (int hh = 0; hh < 2; hh++) {
            int u = lane * 4 + hh * 256;
            float4 k4 = kv[j][hh];
            s += sh_vnv[u + 0] * tanhft(k4.x + sh_qb[u + 0]);
            s += sh_vnv[u + 1] * tanhft(k4.y + sh_qb[u + 1]);
            s += sh_vnv[u + 2] * tanhft(k4.z + sh_qb[u + 2]);
            s += sh_vnv[u + 3] * tanhft(k4.w + sh_qb[u + 3]);
          }
#pragma unroll
          for (int off = 32; off > 0; off >>= 1) s += __shfl_xor(s, off, 64);
          if (lane == 0) sh_sc[tq] = (tq < len) ? s : -1e30f;
        }
      }
      __syncthreads();
      // softmax over 128
      {
        float v = (tid < 128) ? sh_sc[tid] : -1e30f;
        float mx = v;
#pragma unroll
        for (int off = 32; off > 0; off >>= 1) mx = fmaxf(mx, __shfl_xor(mx, off, 64));
        if (lane == 0) sh_r[wave] = mx;
        __syncthreads();
        mx = fmaxf(fmaxf(sh_r[0], sh_r[1]), fmaxf(sh_r[2], sh_r[3]));
        float e = (tid < 128 && tid < len) ? __expf(v - mx) : 0.f;
        float sum = e;
#pragma unroll
        for (int off = 32; off > 0; off >>= 1) sum += __shfl_xor(sum, off, 64);
        if (lane == 0) sh_r[8 + wave] = sum;
        __syncthreads();
        float inv = 1.f / (sh_r[8] + sh_r[9] + sh_r[10] + sh_r[11]);
        if (tid < 128) sh_al[tid] = e * inv;   // 0 for masked entries
      }
      __syncthreads();
      // context = alpha @ enc_out[b] — batched x8; masked rows have alpha=0
      {
        int d = tid * 4;
        float4 acc = make_float4(0.f, 0.f, 0.f, 0.f);
        const float* ep2 = eout + (size_t)b * 128 * 1024 + d;
#pragma unroll 1
        for (int tq0 = 0; tq0 < 128; tq0 += 8) {
          float4 e4[8];
#pragma unroll
          for (int j = 0; j < 8; j++)
            e4[j] = *(const float4*)(ep2 + (size_t)(tq0 + j) * 1024);
#pragma unroll
          for (int j = 0; j < 8; j++) {
            float a = sh_al[tq0 + j];
            acc.x = fmaf(a, e4[j].x, acc.x); acc.y = fmaf(a, e4[j].y, acc.y);
            acc.z = fmaf(a, e4[j].z, acc.z); acc.w = fmaf(a, e4[j].w, acc.w);
          }
        }
        cstore(ctx + b * 1024 + d + 0, acc.x);
        cstore(ctx + b * 1024 + d + 1, acc.y);
        cstore(ctx + b * 1024 + d + 2, acc.z);
        cstore(ctx + b * 1024 + d + 3, acc.w);
      }
    }
    BAR();

    // phase F: attn(t) = (h1|ctx) @ Wal; 8nb x 16kb = 128 blocks, KWIN=96
    if (bid < 128) {
      int nb = bid & 7, kb = bid >> 3;
      stage<96>(at, [&](int m, int kl) -> float {
        int kk = kb * 96 + kl;
        return (kk < 512) ? cload(h1 + m * 512 + kk) : cload(ctx + m * 1024 + kk - 512);
      });
      float acc[32];
#pragma unroll
      for (int m = 0; m < 32; m++) acc[m] = 0.f;
      gemm_frag<96>(Wal, 512, nb * 64 + lane, true, kb * 96, at, acc);
      red_write(red, acc);
      float* adst = attn_s + (size_t)(t & 1) * 16384;
      for (int i = tid; i < 2048; i += NTHR) {
        int m = i >> 6, nn = i & 63;
        atomicAdd(adst + (size_t)m * 512 + nb * 64 + nn, redsum(red, m, nn));
      }
    }
    BAR();
  }

  // trailing copy: attn(127) -> aall[127]  (parity slot 127&1 = 1)
  if (bid >= 384 && bid < 392) {
    const float* asrc = attn_s + (size_t)1 * 16384;
    float v[8];
    int j8 = ((bid - 384) * 256 + tid) * 8;
#pragma unroll
    for (int k = 0; k < 8; k++) v[k] = cload(asrc + j8 + k);
#pragma unroll
    for (int k = 0; k < 8; k++) aall[(size_t)127 * 16384 + j8 + k] = v[k];
  }
  BARSEAL();  // seal aall for cached readers; p0/p1 scratch now dead

  // ---------------- batched projection: out = aall @ Wproj + bproj ----------------
  // nb-stable blocks: Wproj 64-col slice (128 KB) stays L2-resident across 32 t-reuses.
#pragma unroll 1
  for (int task = bid; task < 564; task += NBLKS) {
    int nb = task >> 2, tq = task & 3;  // nb 0..140, tq 0..3
    int n0 = nb * 64;
    const int col = n0 + lane;
    const bool ok = col < 9000;
#pragma unroll 1
    for (int t = tq * 32; t < tq * 32 + 32; t++) {
      const float* asrc = aall + (size_t)t * 16384;
      float acc[32];
#pragma unroll
      for (int m = 0; m < 32; m++) acc[m] = 0.f;
#pragma unroll 1
      for (int c = 0; c < 4; c++) {
        stage<128>(at, [&](int m, int kl) -> float {
          return asrc[(size_t)m * 512 + c * 128 + kl];  // plain cached (sealed)
        });
        gemm_frag<128>(Wproj, 9000, col, ok, c * 128, at, acc);
      }
      red_write(red, acc);
      for (int i = tid; i < 2048; i += NTHR) {
        int m = i >> 6, nn = i & 63;
        int nc = n0 + nn;
        if (nc < 9000)
          out[((size_t)m * 128 + t) * 9000 + nc] = redsum(red, m, nn) + bproj[nc];
      }
    }
  }
#undef BAR
#undef BARSEAL
}

extern "C" void kernel_launch(void* const* d_in, const int* in_sizes, int n_in,
                              void* d_out, int out_size, void* d_ws, size_t ws_size,
                              hipStream_t stream) {
  (void)in_sizes; (void)n_in; (void)out_size; (void)ws_size;
  hipMemsetAsync(d_ws, 0, cfg::MEMSET_BYTES, stream);  // cells + states + attn_s
  hipLaunchKernelGGL(seq2seq_kernel, dim3(NBLKS), dim3(NTHR), 0, stream,
                     (const float*)d_in[0],   // embed_in
                     (const float*)d_in[1],   // dec_embed
                     (const int*)d_in[2],     // in_seq_len
                     (const float*)d_in[3],   // enc_fw_kernel
                     (const float*)d_in[4],   // enc_fw_bias
                     (const float*)d_in[5],   // enc_bw_kernel
                     (const float*)d_in[6],   // enc_bw_bias
                     (const float*)d_in[7],   // dec_kernel0
                     (const float*)d_in[8],   // dec_bias0
                     (const float*)d_in[9],   // dec_kernel1
                     (const float*)d_in[10],  // dec_bias1
                     (const float*)d_in[11],  // w_mem
                     (const float*)d_in[12],  // w_query
                     (const float*)d_in[13],  // b_attn
                     (const float*)d_in[14],  // v_attn
                     (const float*)d_in[15],  // g_attn
                     (const float*)d_in[16],  // w_attn_layer
                     (const float*)d_in[17],  // w_proj
                     (const float*)d_in[18],  // b_proj
                     (float*)d_out, (float*)d_ws);
}